// Round 8
// baseline (1066.808 us; speedup 1.0000x reference)
//
#include <hip/hip_runtime.h>

// LSTM: B=2048, T=4096, I=5, H=10, fp32. One wave per batch chain.
// QUAD LAYOUT: lane = 4*j + k  (j = hidden unit 0..9, k = gate 0..3 = i,f,g,o).
//  - gate gather is DPP quad_perm broadcast (VALU), no LDS pipe on the chain.
//  - W_ih/W_hh/bias pre-scaled by -log2e (-2log2e for g rows); cell carried as
//    cs = -2*log2e*c, so both exp2's consume their inputs directly.
//  - x staged into PADDED LDS (8 floats/step): per-step reads are 1 ds_read_b128
//    + 1 ds_read_b32 (uniform -> broadcast); scatter addrs precomputed.
//  - stores batched 4 steps (capture via cndmask, coalesced 160B store).
// This round (issue diet, kernel is issue-bound at 85% VALUBusy / 2 waves/SIMD):
//  - capture masks (k == u&3) hoisted to loop-invariant bools (kills per-step
//    v_cmp; cndmask reads a precomputed SGPR-pair mask).
//  - x LDS read software-pipelined 1 step ahead (ds_read for u+1 issued during
//    step u; +32B LDS pad makes the one-past-end read benign).
//  - 10 readlanes grouped before the h-FMA tree (max slack on SGPR results).

#define BB 2048
#define TT 4096
#define II 5
#define HH 10
#define CH 256                // timesteps per LDS chunk
#define CHF (CH * II)         // 1280 floats of raw x per chunk
#define PSTRIDE 32            // padded bytes per step in LDS (8 floats)
#define BUFB (CH * PSTRIDE)   // 8192 bytes per buffer
#define NCHUNK (TT / CH)      // 16

__device__ __forceinline__ float readlane_f(float v, int l) {
    union { float f; int i; } u;
    u.f = v;
    u.i = __builtin_amdgcn_readlane(u.i, l);
    return u.f;
}

// Broadcast quad element E to all 4 lanes of each quad (DPP quad_perm).
template<int E>
__device__ __forceinline__ float quad_bcast(float v) {
    union { float f; int i; } u;
    u.f = v;
    u.i = __builtin_amdgcn_update_dpp(u.i, u.i, E * 0x55, 0xF, 0xF, false);
    return u.f;
}

__global__ __launch_bounds__(64) void lstm_wave_kernel(
    const float* __restrict__ x,
    const float* __restrict__ h0,
    const float* __restrict__ c0,
    const float* __restrict__ W_ih,
    const float* __restrict__ W_hh,
    const float* __restrict__ b_ih,
    const float* __restrict__ b_hh,
    float* __restrict__ out)
{
    // 2 buffers contiguous + 32B pad: the pipelined read of step u+1 at the
    // last step touches one slot past the buffer; pad keeps it in-bounds.
    __shared__ __align__(16) char xs[2 * BUFB + 32];

    const int b = blockIdx.x;
    const int lane = threadIdx.x;
    const int j = lane >> 2;       // hidden unit
    const int k = lane & 3;        // gate: 0=i 1=f 2=g 3=o
    const bool active = (lane < 4 * HH);

    const float LOG2E = 1.4426950408889634f;
    const float KC = -2.f * LOG2E;                 // cell carry scale
    const float scale = (k == 2) ? KC : -LOG2E;    // preact scale folded into W

    // Loop-invariant capture masks (one cndmask per step, zero compares)
    const bool mr0 = (k == 0), mr1 = (k == 1), mr2 = (k == 2), mr3 = (k == 3);

    // Per-lane gate-row weights, pre-scaled
    float wih[II];
    float whh[HH];
    float bias = 0.f;
    if (active) {
        const int row = k * HH + j;                // gate blocks of 10 rows: i,f,g,o
#pragma unroll
        for (int q = 0; q < II; q++) wih[q] = W_ih[row * II + q] * scale;
#pragma unroll
        for (int q = 0; q < HH; q++) whh[q] = W_hh[row * HH + q] * scale;
        bias = (b_ih[row] + b_hh[row]) * scale;
    } else {
#pragma unroll
        for (int q = 0; q < II; q++) wih[q] = 0.f;
#pragma unroll
        for (int q = 0; q < HH; q++) whh[q] = 0.f;
    }

    // act = fma(s, am, ac) with s = rcp(1+exp2(acc)):
    //   sigmoid lanes: act = s.   g lane: act = KC*tanh = s*(2KC) + (-KC)
    const float am = (k == 2) ? (2.f * KC) : 1.f;
    const float ac = (k == 2) ? (-KC) : 0.f;

    float hval = 0.f, cs = 0.f;
    if (active) {
        hval = h0[b * HH + j];
        cs   = c0[b * HH + j] * KC;    // carry is KC*c
    }

    const float* xrow = x + (size_t)b * TT * II;

    // Per-lane batched-store pointer: lane (j,k) writes out[b][tb+k][j].
    float* outp = out + (size_t)b * TT * HH + k * HH + j;

    // Precompute the 20 padded-LDS scatter byte-addresses for staging:
    // loaded float4 xv[q*64+lane] component c sits at raw float pos
    // p = (q*64+lane)*4 + c  ->  padded byte (p/5)*32 + (p%5)*4.
    int wa[II][4];
#pragma unroll
    for (int q = 0; q < II; q++) {
#pragma unroll
        for (int c4 = 0; c4 < 4; c4++) {
            const int p = (q * 64 + lane) * 4 + c4;
            wa[q][c4] = (p / II) * PSTRIDE + (p % II) * 4;
        }
    }

    // ---- stage chunk 0 (padded scatter) ----
    float4 pf[II];
    {
        const float4* xv = (const float4*)xrow;
#pragma unroll
        for (int q = 0; q < II; q++) pf[q] = xv[q * 64 + lane];
        char* dst = xs;
#pragma unroll
        for (int q = 0; q < II; q++) {
            *(float*)(dst + wa[q][0]) = pf[q].x;
            *(float*)(dst + wa[q][1]) = pf[q].y;
            *(float*)(dst + wa[q][2]) = pf[q].z;
            *(float*)(dst + wa[q][3]) = pf[q].w;
        }
    }

    float keep = 0.f;   // batched-store capture register

    for (int c = 0; c < NCHUNK; ++c) {
        const char* xc = xs + (c & 1) * BUFB;

        // issue next chunk's global loads now; consume ~256 steps later
        if (c + 1 < NCHUNK) {
            const float4* xv = (const float4*)(xrow + (size_t)(c + 1) * CHF);
#pragma unroll
            for (int q = 0; q < II; q++) pf[q] = xv[q * 64 + lane];
        }

        // software-pipeline preload: x for step u=0 of this chunk
        float4 xv4c = *(const float4*)(xc);
        float  x4c  = *(const float*)(xc + 16);

#pragma unroll 8
        for (int u = 0; u < CH; ++u) {
            // issue next step's x read now (consumed next iteration);
            // at u=CH-1 this reads the pad/next buffer: discarded.
            const float4 xv4n = *(const float4*)(xc + (u + 1) * PSTRIDE);
            const float  x4n  = *(const float*)(xc + (u + 1) * PSTRIDE + 16);

            // h broadcasts first: all 10 readlanes issued together, consumed
            // by the FMA tree with max slack.
            const float hb0 = readlane_f(hval, 0);
            const float hb1 = readlane_f(hval, 4);
            const float hb2 = readlane_f(hval, 8);
            const float hb3 = readlane_f(hval, 12);
            const float hb4 = readlane_f(hval, 16);
            const float hb5 = readlane_f(hval, 20);
            const float hb6 = readlane_f(hval, 24);
            const float hb7 = readlane_f(hval, 28);
            const float hb8 = readlane_f(hval, 32);
            const float hb9 = readlane_f(hval, 36);

            // pre-scaled gate preact: 4-acc tree; x terms land first (off-chain)
            float a0 = fmaf(xv4c.x, wih[0], bias);
            float a1 = xv4c.y * wih[1];
            float a2 = xv4c.z * wih[2];
            float a3 = xv4c.w * wih[3];
            a0 = fmaf(x4c, wih[4], a0);

            a0 = fmaf(hb0, whh[0], a0);
            a1 = fmaf(hb1, whh[1], a1);
            a2 = fmaf(hb2, whh[2], a2);
            a3 = fmaf(hb3, whh[3], a3);
            a0 = fmaf(hb4, whh[4], a0);
            a1 = fmaf(hb5, whh[5], a1);
            a2 = fmaf(hb6, whh[6], a2);
            a3 = fmaf(hb7, whh[7], a3);
            a0 = fmaf(hb8, whh[8], a0);
            a1 = fmaf(hb9, whh[9], a1);
            const float acc = (a0 + a1) + (a2 + a3);

            // branchless sigmoid / KC*tanh
            const float e = __builtin_amdgcn_exp2f(acc);
            const float s = __builtin_amdgcn_rcpf(1.f + e);
            const float act = fmaf(s, am, ac);

            // quad gather: pure-VALU DPP broadcasts
            const float iv = quad_bcast<0>(act);
            const float fv = quad_bcast<1>(act);
            const float gs = quad_bcast<2>(act);   // already KC*g
            const float ov = quad_bcast<3>(act);

            // cs = KC*c:  cs' = f*cs + i*(KC*g);  tanh(c) = 2*rcp(1+exp2(cs))-1
            cs = fmaf(fv, cs, iv * gs);
            const float e2 = __builtin_amdgcn_exp2f(cs);
            const float th = fmaf(__builtin_amdgcn_rcpf(1.f + e2), 2.f, -1.f);
            hval = ov * th;

            // batched store: lane (j,k) captures step ==k (mod 4);
            // mask is a hoisted bool -> single cndmask per step.
            const bool cap = ((u & 3) == 0) ? mr0 :
                             ((u & 3) == 1) ? mr1 :
                             ((u & 3) == 2) ? mr2 : mr3;
            keep = cap ? hval : keep;
            if ((u & 3) == 3) {
                const int off = ((u & 7) == 3) ? 0 : 40;   // imm 0 / 160B
                if (active) outp[off] = keep;
            }
            if ((u & 7) == 7) outp += 80;            // +320B per unroll-8

            // rotate x pipeline
            xv4c = xv4n;
            x4c  = x4n;
        }

        // park the prefetched chunk into the other LDS buffer (padded scatter)
        if (c + 1 < NCHUNK) {
            char* dst = xs + ((c + 1) & 1) * BUFB;
#pragma unroll
            for (int q = 0; q < II; q++) {
                *(float*)(dst + wa[q][0]) = pf[q].x;
                *(float*)(dst + wa[q][1]) = pf[q].y;
                *(float*)(dst + wa[q][2]) = pf[q].z;
                *(float*)(dst + wa[q][3]) = pf[q].w;
            }
        }
    }
}

extern "C" void kernel_launch(void* const* d_in, const int* in_sizes, int n_in,
                              void* d_out, int out_size, void* d_ws, size_t ws_size,
                              hipStream_t stream) {
    const float* x    = (const float*)d_in[0];
    const float* h0   = (const float*)d_in[1];
    const float* c0   = (const float*)d_in[2];
    const float* W_ih = (const float*)d_in[3];
    const float* W_hh = (const float*)d_in[4];
    const float* b_ih = (const float*)d_in[5];
    const float* b_hh = (const float*)d_in[6];
    float* out = (float*)d_out;

    lstm_wave_kernel<<<dim3(BB), dim3(64), 0, stream>>>(
        x, h0, c0, W_ih, W_hh, b_ih, b_hh, out);
}